// Round 3
// baseline (149.416 us; speedup 1.0000x reference)
//
#include <hip/hip_runtime.h>
#include <math.h>

#define NCOL 32
#define DDIM 512
#define NPAIR 16
#define CATS 10
#define ROWS_PER_WAVE 64
#define ROW_STRIDE (NCOL * DDIM) /* 16384 floats between consecutive b rows */

// v += dpp_permuted(v). old=0 / bound_ctrl=false: masked-off rows contribute 0.
template <int CTRL, int ROW_MASK>
__device__ __forceinline__ float dpp_add(float v) {
    int t = __builtin_amdgcn_update_dpp(0, __float_as_int(v), CTRL, ROW_MASK, 0xf, false);
    return v + __int_as_float(t);
}
// pure DPP move: returns permuted value (0 in masked-off rows).
template <int CTRL, int ROW_MASK>
__device__ __forceinline__ float dpp_mov(float v) {
    int t = __builtin_amdgcn_update_dpp(0, __float_as_int(v), CTRL, ROW_MASK, 0xf, false);
    return __int_as_float(t);
}

// After this: lane31 = sum(lanes 0..31), lane63 = sum(lanes 32..63). VALU only.
__device__ __forceinline__ float wave_reduce_halves(float v) {
    v = dpp_add<0x111, 0xf>(v);  // row_shr:1
    v = dpp_add<0x112, 0xf>(v);  // row_shr:2
    v = dpp_add<0x114, 0xf>(v);  // row_shr:4
    v = dpp_add<0x118, 0xf>(v);  // row_shr:8  -> lane15 of each row16 = row sum
    v = dpp_add<0x142, 0xa>(v);  // row_bcast:15 -> lane31, lane63 hold half-sums
    return v;
}
// Full 64-lane sum, valid in lane 63.
__device__ __forceinline__ float wave_reduce_full(float v) {
    v = wave_reduce_halves(v);
    v = dpp_add<0x143, 0xc>(v);  // row_bcast:31 into rows 2,3 -> lane63 = total
    return v;
}

#define LOADROW(Ra, Rb, r) do {                                   \
    const float* _p = xb + (size_t)(r) * ROW_STRIDE;              \
    Ra = *(const float4*)(_p + lane * 4);                         \
    Rb = *(const float4*)(_p + 256 + lane * 4);                   \
} while (0)

// ---------------------------------------------------------------- numeric
#define NUM_ROW(Ra, Rb, idx) do {                                 \
    float s = Ra.x * w[0];                                        \
    s = fmaf(Ra.y, w[1], s);                                      \
    s = fmaf(Ra.z, w[2], s);                                      \
    s = fmaf(Ra.w, w[3], s);                                      \
    s = fmaf(Rb.x, w[4], s);                                      \
    s = fmaf(Rb.y, w[5], s);                                      \
    s = fmaf(Rb.z, w[6], s);                                      \
    s = fmaf(Rb.w, w[7], s);                                      \
    s = wave_reduce_full(s);                                      \
    if (lane == 63) ob[(size_t)(idx) * NCOL] = tanhf(s + bias);   \
} while (0)

__global__ __launch_bounds__(256, 4) void num_kernel(
    const float* __restrict__ x,
    const float* __restrict__ Wn,
    const float* __restrict__ bn,
    float* __restrict__ out)
{
    const int lane  = threadIdx.x & 63;
    const int wslot = threadIdx.x >> 6;
    const int wid   = __builtin_amdgcn_readfirstlane(blockIdx.x * 4 + wslot); // 0..2047
    const int p     = wid & (NPAIR - 1);
    const int chunk = wid >> 4;                       // 0..127
    const size_t b0 = (size_t)chunk * ROWS_PER_WAVE;

    float w[8];
    {
        float4 wa = *(const float4*)(Wn + p * DDIM + lane * 4);
        float4 wb = *(const float4*)(Wn + p * DDIM + 256 + lane * 4);
        w[0]=wa.x; w[1]=wa.y; w[2]=wa.z; w[3]=wa.w;
        w[4]=wb.x; w[5]=wb.y; w[6]=wb.z; w[7]=wb.w;
    }
    const float bias = __int_as_float(
        __builtin_amdgcn_readfirstlane(__float_as_int(bn[p])));
    const float* xb = x + b0 * ROW_STRIDE + (size_t)(2 * p) * DDIM;
    float* ob = out + b0 * NCOL + 2 * p;

    // depth-8 rotating named buffers: ~16 KB in flight per wave
    float4 R0a,R0b,R1a,R1b,R2a,R2b,R3a,R3b,R4a,R4b,R5a,R5b,R6a,R6b,R7a,R7b;
    LOADROW(R0a,R0b,0); LOADROW(R1a,R1b,1); LOADROW(R2a,R2b,2); LOADROW(R3a,R3b,3);
    LOADROW(R4a,R4b,4); LOADROW(R5a,R5b,5); LOADROW(R6a,R6b,6); LOADROW(R7a,R7b,7);

    for (int i = 0; i < 56; i += 8) {
        NUM_ROW(R0a,R0b,i+0); LOADROW(R0a,R0b,i+8);
        NUM_ROW(R1a,R1b,i+1); LOADROW(R1a,R1b,i+9);
        NUM_ROW(R2a,R2b,i+2); LOADROW(R2a,R2b,i+10);
        NUM_ROW(R3a,R3b,i+3); LOADROW(R3a,R3b,i+11);
        NUM_ROW(R4a,R4b,i+4); LOADROW(R4a,R4b,i+12);
        NUM_ROW(R5a,R5b,i+5); LOADROW(R5a,R5b,i+13);
        NUM_ROW(R6a,R6b,i+6); LOADROW(R6a,R6b,i+14);
        NUM_ROW(R7a,R7b,i+7); LOADROW(R7a,R7b,i+15);
    }
    // peeled tail: rows 56..63, no reloads
    NUM_ROW(R0a,R0b,56); NUM_ROW(R1a,R1b,57); NUM_ROW(R2a,R2b,58); NUM_ROW(R3a,R3b,59);
    NUM_ROW(R4a,R4b,60); NUM_ROW(R5a,R5b,61); NUM_ROW(R6a,R6b,62); NUM_ROW(R7a,R7b,63);
}

// ---------------------------------------------------------------- categorical
#define CAT_ROW(Ra, Rb, idx) do {                                 \
    double best = -1.0e300;                                       \
    int bi = 0;                                                   \
    _Pragma("unroll")                                             \
    for (int c = 0; c < CATS; ++c) {                              \
        float s = Ra.x * wc[c];                                   \
        s = fmaf(Ra.y, wc[10 + c], s);                            \
        s = fmaf(Ra.z, wc[20 + c], s);                            \
        s = fmaf(Ra.w, wc[30 + c], s);                            \
        s = fmaf(Rb.x, wc[40 + c], s);                            \
        s = fmaf(Rb.y, wc[50 + c], s);                            \
        s = fmaf(Rb.z, wc[60 + c], s);                            \
        s = fmaf(Rb.w, wc[70 + c], s);                            \
        s = wave_reduce_halves(s);                                \
        float slo = dpp_mov<0x143, 0xc>(s);                       \
        double d = (double)s + (double)slo + biasd[c];            \
        if (d > best) { best = d; bi = c; }                       \
    }                                                             \
    if (lane == 63) ob[(size_t)(idx) * NCOL] = (float)bi;         \
} while (0)

__global__ __launch_bounds__(256, 3) void cat_kernel(
    const float* __restrict__ x,
    const float* __restrict__ Wc,
    const float* __restrict__ bc,
    float* __restrict__ out)
{
    const int lane  = threadIdx.x & 63;
    const int wslot = threadIdx.x >> 6;
    const int wid   = __builtin_amdgcn_readfirstlane(blockIdx.x * 4 + wslot); // 0..2047
    const int p     = wid & (NPAIR - 1);
    const int chunk = wid >> 4;
    const size_t b0 = (size_t)chunk * ROWS_PER_WAVE;

    float wc[80];  // wc[dd*10+c] low half (d=4*lane+dd), wc[40+dd*10+c] high half
    {
        const float* w0 = Wc + ((size_t)p * DDIM + lane * 4) * CATS;
        const float* w1 = Wc + ((size_t)p * DDIM + 256 + lane * 4) * CATS;
        #pragma unroll
        for (int k = 0; k < 10; ++k) {
            float4 t = *(const float4*)(w0 + k * 4);
            wc[4*k] = t.x; wc[4*k+1] = t.y; wc[4*k+2] = t.z; wc[4*k+3] = t.w;
        }
        #pragma unroll
        for (int k = 0; k < 10; ++k) {
            float4 t = *(const float4*)(w1 + k * 4);
            wc[40+4*k] = t.x; wc[40+4*k+1] = t.y; wc[40+4*k+2] = t.z; wc[40+4*k+3] = t.w;
        }
    }
    double biasd[CATS];  // wave-uniform -> SGPR pairs
    #pragma unroll
    for (int c = 0; c < CATS; ++c)
        biasd[c] = (double)__int_as_float(
            __builtin_amdgcn_readfirstlane(__float_as_int(bc[p * CATS + c])));

    const float* xb = x + b0 * ROW_STRIDE + (size_t)(2 * p + 1) * DDIM;
    float* ob = out + b0 * NCOL + 2 * p + 1;

    // depth-4 rotating named buffers: ~8 KB in flight per wave
    float4 R0a,R0b,R1a,R1b,R2a,R2b,R3a,R3b;
    LOADROW(R0a,R0b,0); LOADROW(R1a,R1b,1); LOADROW(R2a,R2b,2); LOADROW(R3a,R3b,3);

    for (int i = 0; i < 60; i += 4) {
        CAT_ROW(R0a,R0b,i+0); LOADROW(R0a,R0b,i+4);
        CAT_ROW(R1a,R1b,i+1); LOADROW(R1a,R1b,i+5);
        CAT_ROW(R2a,R2b,i+2); LOADROW(R2a,R2b,i+6);
        CAT_ROW(R3a,R3b,i+3); LOADROW(R3a,R3b,i+7);
    }
    // peeled tail: rows 60..63
    CAT_ROW(R0a,R0b,60); CAT_ROW(R1a,R1b,61); CAT_ROW(R2a,R2b,62); CAT_ROW(R3a,R3b,63);
}

extern "C" void kernel_launch(void* const* d_in, const int* in_sizes, int n_in,
                              void* d_out, int out_size, void* d_ws, size_t ws_size,
                              hipStream_t stream) {
    const float* x  = (const float*)d_in[0];
    const float* Wn = (const float*)d_in[1];
    const float* bn = (const float*)d_in[2];
    const float* Wc = (const float*)d_in[3];
    const float* bc = (const float*)d_in[4];
    float* out = (float*)d_out;

    dim3 block(256);
    hipLaunchKernelGGL(num_kernel, dim3(512), block, 0, stream, x, Wn, bn, out);
    hipLaunchKernelGGL(cat_kernel, dim3(512), block, 0, stream, x, Wc, bc, out);
}